// Round 1
// baseline (658.406 us; speedup 1.0000x reference)
//
#include <hip/hip_runtime.h>
#include <hip/hip_bf16.h>
#include <stdint.h>

// Problem shape (fixed by reference): M=8192 (8 shards x 1024), K=N=4096.
// C[m,n] = sum_k A[m,k] * W[n,k]  (weight stored [N,K], transed_weight==0)
#define K_DIM 4096
#define N_DIM 4096

typedef short short8 __attribute__((ext_vector_type(8)));      // 8 bf16 = 4 VGPRs (MFMA A/B frag)
typedef float f32x4 __attribute__((ext_vector_type(4)));       // MFMA C/D frag
typedef unsigned short ushort_t;
typedef unsigned short ushort8 __attribute__((ext_vector_type(8)));

// fp32 -> bf16 round-to-nearest-even (bit trick, no header dependency)
__device__ __forceinline__ ushort_t f2bf(float f) {
    uint32_t u = __float_as_uint(f);
    u += 0x7FFFu + ((u >> 16) & 1u);
    return (ushort_t)(u >> 16);
}

// Cast n8*8 fp32 elements to bf16. 8 elems/thread: 2x float4 loads, 1x 16B store.
__global__ void cast_to_bf16(const float* __restrict__ in, ushort_t* __restrict__ out, int n8) {
    int i = blockIdx.x * blockDim.x + threadIdx.x;
    if (i >= n8) return;
    const float4* p = (const float4*)in + (size_t)i * 2;
    float4 v0 = p[0];
    float4 v1 = p[1];
    ushort8 r;
    r[0] = f2bf(v0.x); r[1] = f2bf(v0.y); r[2] = f2bf(v0.z); r[3] = f2bf(v0.w);
    r[4] = f2bf(v1.x); r[5] = f2bf(v1.y); r[6] = f2bf(v1.z); r[7] = f2bf(v1.w);
    *((ushort8*)out + i) = r;
}

// m97-pattern bf16 GEMM, B^T layout. 128x128 tile, BK=32, 256 threads (4 waves 2x2),
// each wave does a 64x64 sub-tile as 4x4 MFMA 16x16x32 tiles.
__global__ __launch_bounds__(256) void gemm_bf16_bt(
    const ushort_t* __restrict__ A,   // [M][K] bf16
    const ushort_t* __restrict__ B,   // [N][K] bf16 (weight as stored)
    float* __restrict__ C)            // [M][N] fp32
{
    __shared__ ushort_t lds_a[128 * 32];   // 8 KB, contiguous rows of 32 bf16 (64 B)
    __shared__ ushort_t lds_b[128 * 32];

    const int lane = threadIdx.x & 63;
    const int wave = threadIdx.x >> 6;
    const int tile_m = blockIdx.y * 128;
    const int tile_n = blockIdx.x * 128;

    const int wm = (wave >> 1) * 64;   // wave's m-offset within tile
    const int wn = (wave & 1) * 64;    // wave's n-offset within tile

    const int row16 = lane & 15;
    const int quad  = lane >> 4;

    f32x4 acc[4][4] = {};

    for (int k0 = 0; k0 < K_DIM; k0 += 32) {
        // Stage A/B tiles: 512 chunks of 16B each per tile; chunk c -> row c>>2, k-col (c&3)*8.
        // global_load_lds: LDS dst is wave-uniform base + lane*16 -> chunk = base + lane.
        #pragma unroll
        for (int i = 0; i < 2; ++i) {
            int c   = wave * 128 + i * 64 + lane;
            int row = c >> 2;
            int kc  = (c & 3) * 8;
            const ushort_t* ga = A + (size_t)(tile_m + row) * K_DIM + k0 + kc;
            const ushort_t* gb = B + (size_t)(tile_n + row) * K_DIM + k0 + kc;
            int base = (wave * 128 + i * 64) * 8;   // ushort units; wave-uniform
            __builtin_amdgcn_global_load_lds(
                (const __attribute__((address_space(1))) void*)ga,
                (__attribute__((address_space(3))) void*)(lds_a + base), 16, 0, 0);
            __builtin_amdgcn_global_load_lds(
                (const __attribute__((address_space(1))) void*)gb,
                (__attribute__((address_space(3))) void*)(lds_b + base), 16, 0, 0);
        }
        __syncthreads();   // compiler drains vmcnt(0) before s_barrier

        // Fragment loads: A[m=lane&15][k=quad*8+j], B^T rows likewise -> ds_read_b128
        short8 a_frag[4], b_frag[4];
        #pragma unroll
        for (int t = 0; t < 4; ++t) {
            a_frag[t] = *(const short8*)(lds_a + (wm + t * 16 + row16) * 32 + quad * 8);
            b_frag[t] = *(const short8*)(lds_b + (wn + t * 16 + row16) * 32 + quad * 8);
        }
        #pragma unroll
        for (int mi = 0; mi < 4; ++mi)
            #pragma unroll
            for (int ni = 0; ni < 4; ++ni)
                acc[mi][ni] = __builtin_amdgcn_mfma_f32_16x16x32_bf16(
                    a_frag[mi], b_frag[ni], acc[mi][ni], 0, 0, 0);

        __syncthreads();   // protect LDS from next iteration's staging
    }

    // Epilogue: C/D layout col=lane&15, row=quad*4+reg (m89/m91-verified)
    #pragma unroll
    for (int mi = 0; mi < 4; ++mi) {
        #pragma unroll
        for (int r = 0; r < 4; ++r) {
            int m = tile_m + wm + mi * 16 + quad * 4 + r;
            float* crow = C + (size_t)m * N_DIM + tile_n + wn;
            #pragma unroll
            for (int ni = 0; ni < 4; ++ni)
                crow[ni * 16 + row16] = acc[mi][ni][r];
        }
    }
}

// Safety-net fallback if ws_size can't hold bf16 copies (not expected to trigger).
__global__ void gemm_naive_f32(const float* __restrict__ A, const float* __restrict__ W,
                               float* __restrict__ C, int m_tot) {
    int n = blockIdx.x * blockDim.x + threadIdx.x;
    int m = blockIdx.y;
    if (n >= N_DIM || m >= m_tot) return;
    const float* a = A + (size_t)m * K_DIM;
    const float* w = W + (size_t)n * K_DIM;
    float s = 0.f;
    for (int k = 0; k < K_DIM; ++k) s += a[k] * w[k];
    C[(size_t)m * N_DIM + n] = s;
}

extern "C" void kernel_launch(void* const* d_in, const int* in_sizes, int n_in,
                              void* d_out, int out_size, void* d_ws, size_t ws_size,
                              hipStream_t stream) {
    const float* a_f32 = (const float*)d_in[0];   // [8,1024,4096] == [8192,4096]
    const float* w_f32 = (const float*)d_in[1];   // [4096,4096] ([N,K])
    float* out = (float*)d_out;

    const size_t a_elems = (size_t)in_sizes[0];
    const size_t w_elems = (size_t)in_sizes[1];
    const int m_tot = (int)(a_elems / K_DIM);     // 8192

    const size_t need = (a_elems + w_elems) * sizeof(ushort_t);
    if (ws_size >= need) {
        ushort_t* a_bf = (ushort_t*)d_ws;
        ushort_t* w_bf = a_bf + a_elems;

        int n8a = (int)(a_elems / 8);
        int n8w = (int)(w_elems / 8);
        cast_to_bf16<<<(n8a + 255) / 256, 256, 0, stream>>>(a_f32, a_bf, n8a);
        cast_to_bf16<<<(n8w + 255) / 256, 256, 0, stream>>>(w_f32, w_bf, n8w);

        dim3 grid(N_DIM / 128, m_tot / 128);      // (32, 64)
        gemm_bf16_bt<<<grid, 256, 0, stream>>>(a_bf, w_bf, out);
    } else {
        dim3 grid(N_DIM / 256, m_tot);
        gemm_naive_f32<<<grid, 256, 0, stream>>>(a_f32, w_f32, out, m_tot);
    }
}